// Round 9
// baseline (377.690 us; speedup 1.0000x reference)
//
#include <hip/hip_runtime.h>
#include <hip/hip_fp16.h>
#include <hip/hip_cooperative_groups.h>

namespace cg = cooperative_groups;

#define N_NODES 50000
#define N_EDGES 800000
#define IN_DIM  64
#define OUT_DIM 32
#define FEAT    64                   // B*OUT per node, node-major [N][B][OUT]
#define NODES_PER_BIN 32
#define NBINS   1563                 // ceil(50000/32)
#define NCLS    8                    // XCD classes (blockIdx & 7)
#define CLS_CAP 128                  // per (bin,class): mean 64, P(>=128) ~ 2e-11
#define BIN_SLOTS (NCLS * CLS_CAP)   // 1024
#define NCURS   (NBINS * NCLS)       // 12504
#define SCATTER_CHUNKS (N_EDGES / 256)            // 3125
#define FC_CHUNKS (N_NODES / 8)                   // 6250
#define P1_CHUNKS (SCATTER_CHUNKS + FC_CHUNKS)    // 9375
#define ACCUM_CHUNKS (NBINS * 4)                  // 6252
#define MAX_GRID 2048

// One cooperative kernel, three phases separated by grid.sync():
//   P0: zero cursors (replaces hipMemsetAsync node)
//   P1: grid-stride scatter (XCD-class partitioned) + fc (Wfc staged once/block)
//   P2: grid-stride accum (per-bin LDS counting sort + register accumulation)
__global__ __launch_bounds__(256, 8) void mega_kernel(
    const float* __restrict__ h, const float* __restrict__ weight,
    const int* __restrict__ src, const int* __restrict__ dst,
    const float* __restrict__ Wfc, const float* __restrict__ bfc,
    const float* __restrict__ Watt, const float* __restrict__ batt,
    float* __restrict__ out, float4* __restrict__ a_tab,
    unsigned int* __restrict__ payload, int* __restrict__ cursor,
    __half* __restrict__ ezh) {
  cg::grid_group grid = cg::this_grid();
  __shared__ __align__(16) unsigned char smem[12544];   // 12.25 KB arena
  // phase-1 view: Wl[2048] floats (8 KB) + hs4[8][2][16] float4 (4 KB)
  float*  Wl  = (float*)smem;
  float4* hs4 = (float4*)(smem + 8192);
  // phase-2 view: rec[1024] + sorted[1024] u32 (8 KB) + small int arrays
  unsigned int* rec    = (unsigned int*)smem;
  unsigned int* sorted = (unsigned int*)(smem + 4096);
  int* c8   = (int*)(smem + 8192);
  int* hist = (int*)(smem + 8192 + 32);
  int* off  = (int*)(smem + 8192 + 32 + 128);
  int* cnt2 = (int*)(smem + 8192 + 32 + 256);

  int t = threadIdx.x;
  int nblocks = gridDim.x;
  int w = t >> 6, lane = t & 63, o = lane & 31, b = lane >> 5;

  // ---- phase 0: zero cursors ----
  for (int i = blockIdx.x * 256 + t; i < NCURS; i += nblocks * 256) cursor[i] = 0;
  // stage Wfc once per persistent block (readers sync inside fc chunks)
  for (int i = t; i < 512; i += 256) ((float4*)Wl)[i] = ((const float4*)Wfc)[i];
  grid.sync();

  // ---- phase 1: scatter + fc ----
  int cls = blockIdx.x & 7;   // nblocks is a multiple of 8 => chunk&7 == cls
  for (int chunk = blockIdx.x; chunk < P1_CHUNKS; chunk += nblocks) {
    if (chunk < SCATTER_CHUNKS) {
      int e = chunk * 256 + t;             // exact coverage
      int s = src[e], d = dst[e];
      float wv = weight[e];
      unsigned int wq = (unsigned int)__float2int_rn(wv * 2047.0f) & 2047u;
      unsigned int rc = ((unsigned int)s << 16) | ((unsigned int)(d & 31) << 11) | wq;
      int bin = d >> 5;
      int pos = atomicAdd(&cursor[bin * NCLS + cls], 1);
      if (pos < CLS_CAP)
        payload[(size_t)bin * BIN_SLOTS + cls * CLS_CAP + pos] = rc;
    } else {
      int n0 = (chunk - SCATTER_CHUNKS) * 8;
      __syncthreads();   // previous chunk's readers done; Wl staged
      { int ns = t >> 5, r5 = t & 31, sb = r5 >> 4, i4 = r5 & 15;
        hs4[(ns * 2 + sb) * 16 + i4] =
            ((const float4*)h)[((size_t)sb * N_NODES + (n0 + ns)) * 16 + i4]; }
      __syncthreads();
      int nsA = 2 * w, nsB = nsA + 1;
      float bo = bfc[o];
      float accA = bo, accB = bo;
#pragma unroll
      for (int i4 = 0; i4 < 16; ++i4) {
        float4 hA = hs4[(nsA * 2 + b) * 16 + i4];
        float4 hB = hs4[(nsB * 2 + b) * 16 + i4];
        float w0 = Wl[(i4 * 4 + 0) * OUT_DIM + o];
        float w1 = Wl[(i4 * 4 + 1) * OUT_DIM + o];
        float w2 = Wl[(i4 * 4 + 2) * OUT_DIM + o];
        float w3 = Wl[(i4 * 4 + 3) * OUT_DIM + o];
        accA = fmaf(hA.x, w0, accA); accA = fmaf(hA.y, w1, accA);
        accA = fmaf(hA.z, w2, accA); accA = fmaf(hA.w, w3, accA);
        accB = fmaf(hB.x, w0, accB); accB = fmaf(hB.y, w1, accB);
        accB = fmaf(hB.z, w2, accB); accB = fmaf(hB.w, w3, accB);
      }
      int nA = n0 + nsA, nB = n0 + nsB;
      ezh[(size_t)nA * FEAT + lane] = __float2half(__expf(accA));
      ezh[(size_t)nB * FEAT + lane] = __float2half(__expf(accB));
      float wo1 = Watt[o], wo2 = Watt[OUT_DIM + o];
      float psA = accA * wo1, pdA = accA * wo2;
      float psB = accB * wo1, pdB = accB * wo2;
#pragma unroll
      for (int m = 16; m >= 1; m >>= 1) {
        psA += __shfl_xor(psA, m, 64); pdA += __shfl_xor(pdA, m, 64);
        psB += __shfl_xor(psB, m, 64); pdB += __shfl_xor(pdB, m, 64);
      }
      if (o == 0) {
        ((float2*)(a_tab + nA))[b] = make_float2(psA, pdA);
        ((float2*)(a_tab + nB))[b] = make_float2(psB, pdB);
      }
    }
  }
  grid.sync();

  // ---- phase 2: accum ----
  const float* a_tabf = (const float*)a_tab;   // scalar view: [n*4 + b*2 + {0,1}]
  float wA = Watt[2 * OUT_DIM];
  float bA = batt[0];
  const float kInvQ = 1.0f / 2047.0f;
  for (int c = blockIdx.x; c < ACCUM_CHUNKS; c += nblocks) {
    int bin = c >> 2, quad = c & 3;
    __syncthreads();                 // protect rec/sorted reuse across chunks
    if (t < NCLS) {
      int cc = cursor[bin * NCLS + t];
      c8[t] = cc > CLS_CAP ? CLS_CAP : cc;
    }
    if (t < 32) { hist[t] = 0; cnt2[t] = 0; }
    __syncthreads();
    const unsigned int* seg = payload + (size_t)bin * BIN_SLOTS;
    for (int j = t; j < BIN_SLOTS; j += 256) {
      unsigned int r = seg[j];
      rec[j] = r;
      if ((j & (CLS_CAP - 1)) < c8[j >> 7]) atomicAdd(&hist[(r >> 11) & 31], 1);
    }
    __syncthreads();
    if (t < 64) {  // exclusive shuffle scan of 32 counts (wave 0)
      int v = (t < 32) ? hist[t] : 0;
      int orig = v;
#pragma unroll
      for (int d1 = 1; d1 < 32; d1 <<= 1) {
        int x = __shfl_up(v, d1, 64);
        if (t >= d1) v += x;
      }
      if (t < 32) off[t] = v - orig;
    }
    __syncthreads();
    for (int j = t; j < BIN_SLOTS; j += 256) {
      if ((j & (CLS_CAP - 1)) < c8[j >> 7]) {
        unsigned int r = rec[j];
        int nl = (r >> 11) & 31;
        sorted[off[nl] + atomicAdd(&cnt2[nl], 1)] = r;
      }
    }
    __syncthreads();
#pragma unroll
    for (int k = 0; k < 2; ++k) {
      int nl = quad * 8 + w * 2 + k;           // wave-uniform
      int n = bin * NODES_PER_BIN + nl;
      if (n >= N_NODES) break;
      int cn = hist[nl];
      int base = off[nl];
      float adst = a_tabf[n * 4 + b * 2 + 1];  // a_d[n,b]
      float num = 0.f, den = 0.f;
      int i = 0;
      for (; i + 3 < cn; i += 4) {
        unsigned int r0 = sorted[base + i],     r1 = sorted[base + i + 1];
        unsigned int r2 = sorted[base + i + 2], r3 = sorted[base + i + 3];
        int s0 = r0 >> 16, s1 = r1 >> 16, s2 = r2 >> 16, s3 = r3 >> 16;
        float ez0 = __half2float(ezh[(size_t)s0 * FEAT + lane]);
        float ez1 = __half2float(ezh[(size_t)s1 * FEAT + lane]);
        float ez2 = __half2float(ezh[(size_t)s2 * FEAT + lane]);
        float ez3 = __half2float(ezh[(size_t)s3 * FEAT + lane]);
        float l0 = a_tabf[s0 * 4 + b * 2] + adst + fmaf((r0 & 2047u) * kInvQ, wA, bA);
        float l1 = a_tabf[s1 * 4 + b * 2] + adst + fmaf((r1 & 2047u) * kInvQ, wA, bA);
        float l2 = a_tabf[s2 * 4 + b * 2] + adst + fmaf((r2 & 2047u) * kInvQ, wA, bA);
        float l3 = a_tabf[s3 * 4 + b * 2] + adst + fmaf((r3 & 2047u) * kInvQ, wA, bA);
        l0 = l0 > 0.f ? l0 : 0.01f * l0;
        l1 = l1 > 0.f ? l1 : 0.01f * l1;
        l2 = l2 > 0.f ? l2 : 0.01f * l2;
        l3 = l3 > 0.f ? l3 : 0.01f * l3;
        num = fmaf(ez0, l0, num); den += ez0;
        num = fmaf(ez1, l1, num); den += ez1;
        num = fmaf(ez2, l2, num); den += ez2;
        num = fmaf(ez3, l3, num); den += ez3;
      }
      for (; i < cn; ++i) {
        unsigned int r = sorted[base + i];
        int s = r >> 16;
        float ez = __half2float(ezh[(size_t)s * FEAT + lane]);
        float l = a_tabf[s * 4 + b * 2] + adst + fmaf((r & 2047u) * kInvQ, wA, bA);
        l = l > 0.f ? l : 0.01f * l;
        num = fmaf(ez, l, num); den += ez;
      }
      float v = (cn > 0) ? num / den : 0.f;
      out[((size_t)b * N_NODES + n) * OUT_DIM + o] = v;
    }
  }
}

extern "C" void kernel_launch(void* const* d_in, const int* in_sizes, int n_in,
                              void* d_out, int out_size, void* d_ws, size_t ws_size,
                              hipStream_t stream) {
  const float* h      = (const float*)d_in[0];
  const float* weight = (const float*)d_in[1];
  const int*   src    = (const int*)d_in[2];
  const int*   dst    = (const int*)d_in[3];
  const float* Wfc    = (const float*)d_in[4];
  const float* bfc    = (const float*)d_in[5];
  const float* Watt   = (const float*)d_in[6];
  const float* batt   = (const float*)d_in[7];
  float* out = (float*)d_out;

  // workspace (~13.7 MB), same as R7
  float4*       a_tab   = (float4*)d_ws;                                  // 800 KB
  unsigned int* payload = (unsigned int*)(a_tab + N_NODES);               // 6.4 MB
  __half*       ezh     = (__half*)(payload + (size_t)NBINS * BIN_SLOTS); // 6.4 MB
  int*          cursor  = (int*)(ezh + (size_t)N_NODES * FEAT);           // ~50 KB

  // co-resident grid sizing (host-side queries: capture-safe, deterministic)
  int maxb = 0;
  if (hipOccupancyMaxActiveBlocksPerMultiprocessor(&maxb, mega_kernel, 256, 0)
          != hipSuccess || maxb < 1)
    maxb = 2;
  int dev = 0, cus = 256;
  (void)hipGetDevice(&dev);
  (void)hipDeviceGetAttribute(&cus, hipDeviceAttributeMultiprocessorCount, dev);
  long long g = (long long)maxb * (long long)cus;
  if (g > MAX_GRID) g = MAX_GRID;
  if (g < 8) g = 8;
  g &= ~7LL;   // multiple of 8 so cls = blockIdx&7 partitions evenly

  void* args[] = {(void*)&h, (void*)&weight, (void*)&src, (void*)&dst,
                  (void*)&Wfc, (void*)&bfc, (void*)&Watt, (void*)&batt,
                  (void*)&out, (void*)&a_tab, (void*)&payload, (void*)&cursor,
                  (void*)&ezh};
  (void)hipLaunchCooperativeKernel((void*)mega_kernel, dim3((unsigned)g),
                                   dim3(256), args, 0, stream);
}

// Round 10
// 183.830 us; speedup vs baseline: 2.0546x; 2.0546x over previous
//
#include <hip/hip_runtime.h>
#include <hip/hip_fp16.h>

#define N_NODES 50000
#define N_EDGES 800000
#define IN_DIM  64
#define OUT_DIM 32
#define FEAT    64                   // B*OUT per node
#define NODES_PER_BIN 32
#define NBINS   1563                 // ceil(50000/32)
#define NCLS    8                    // XCD classes (blockIdx & 7)
#define CLS_CAP 128                  // per (bin,class): mean ~64, +8 sigma
#define BIN_SLOTS (NCLS * CLS_CAP)   // 1024
#define NCURS   (NBINS * NCLS)       // 12504
#define EDGES_PER_SBLOCK 512
#define SCATTER_BLOCKS ((N_EDGES + EDGES_PER_SBLOCK - 1) / EDGES_PER_SBLOCK)  // 1563
#define FC_NODES_PER_BLOCK 16
#define FC_BLOCKS (N_NODES / FC_NODES_PER_BLOCK)  // 3125

// Fused K1: scatter blocks first (latency-bound, 2 edges/thread for MLP),
// then fc blocks (16 nodes/block, Wfc staged once per block).
// ezh layout: half2 per (n,o) = {exp(z[n,0,o]), exp(z[n,1,o])}  (batch-interleaved)
// a_tab[n] = float4 {a_s(b0), a_d(b0), a_s(b1), a_d(b1)}
__global__ __launch_bounds__(256) void fused_fc_scatter_kernel(
    const float* __restrict__ h, const float* __restrict__ Wfc,
    const float* __restrict__ bfc, const float* __restrict__ Watt,
    const int* __restrict__ src, const int* __restrict__ dst,
    const float* __restrict__ weight,
    __half2* __restrict__ ezh2, float4* __restrict__ a_tab,
    int* __restrict__ cursor, unsigned int* __restrict__ payload) {
  __shared__ float Wl[IN_DIM * OUT_DIM];                    // 8 KB
  __shared__ float4 hs4[FC_NODES_PER_BLOCK * 2 * 16];       // 8 KB
  int t = threadIdx.x;

  if (blockIdx.x < SCATTER_BLOCKS) {
    // ---- scatter role: two independent chains per lane ----
    int cls = blockIdx.x & 7;
    int e0 = blockIdx.x * EDGES_PER_SBLOCK + t;   // always < N_EDGES
    int e1 = e0 + 256;
    int s0 = src[e0], d0 = dst[e0];
    float w0 = weight[e0];
    unsigned int rec0 = ((unsigned int)s0 << 16) | ((unsigned int)(d0 & 31) << 11) |
                        ((unsigned int)__float2int_rn(w0 * 2047.0f) & 2047u);
    int pos0 = atomicAdd(&cursor[(d0 >> 5) * NCLS + cls], 1);
    if (e1 < N_EDGES) {
      int s1 = src[e1], d1 = dst[e1];
      float w1 = weight[e1];
      unsigned int rec1 = ((unsigned int)s1 << 16) | ((unsigned int)(d1 & 31) << 11) |
                          ((unsigned int)__float2int_rn(w1 * 2047.0f) & 2047u);
      int pos1 = atomicAdd(&cursor[(d1 >> 5) * NCLS + cls], 1);
      if (pos1 < CLS_CAP)
        payload[(size_t)(d1 >> 5) * BIN_SLOTS + cls * CLS_CAP + pos1] = rec1;
    }
    if (pos0 < CLS_CAP)
      payload[(size_t)(d0 >> 5) * BIN_SLOTS + cls * CLS_CAP + pos0] = rec0;
    return;
  }

  // ---- fc role: 16 nodes per block ----
  int n0 = (blockIdx.x - SCATTER_BLOCKS) * FC_NODES_PER_BLOCK;
  for (int i = t; i < 512; i += 256)
    ((float4*)Wl)[i] = ((const float4*)Wfc)[i];
#pragma unroll
  for (int f = t; f < FC_NODES_PER_BLOCK * 2 * 16; f += 256) {
    int ns = f >> 5, sb = (f >> 4) & 1, i4 = f & 15;
    hs4[f] = ((const float4*)h)[((size_t)sb * N_NODES + (n0 + ns)) * 16 + i4];
  }
  __syncthreads();
  int w = t >> 6, lane = t & 63, o = lane & 31, b = lane >> 5;
  float bo = bfc[o];
  float wo1 = Watt[o], wo2 = Watt[OUT_DIM + o];
#pragma unroll
  for (int k = 0; k < 4; ++k) {
    int ns = w * 4 + k;
    int n = n0 + ns;
    float acc = bo;
#pragma unroll
    for (int i4 = 0; i4 < 16; ++i4) {
      float4 hv = hs4[(ns * 2 + b) * 16 + i4];
      acc = fmaf(hv.x, Wl[(i4 * 4 + 0) * OUT_DIM + o], acc);
      acc = fmaf(hv.y, Wl[(i4 * 4 + 1) * OUT_DIM + o], acc);
      acc = fmaf(hv.z, Wl[(i4 * 4 + 2) * OUT_DIM + o], acc);
      acc = fmaf(hv.w, Wl[(i4 * 4 + 3) * OUT_DIM + o], acc);
    }
    float ez = __expf(acc);
    float ezo = __shfl(ez, lane ^ 32, 64);       // partner batch's value
    if (b == 0) {                                // lanes 0-31: 4B half2 store
      __half2 hv2;
      hv2.x = __float2half(ez);
      hv2.y = __float2half(ezo);
      ezh2[(size_t)n * OUT_DIM + o] = hv2;
    }
    float ps = acc * wo1, pd = acc * wo2;
#pragma unroll
    for (int m = 16; m >= 1; m >>= 1) {
      ps += __shfl_xor(ps, m, 64);
      pd += __shfl_xor(pd, m, 64);
    }
    if (o == 0) ((float2*)(a_tab + n))[b] = make_float2(ps, pd);
  }
}

// K2: 4 blocks per bin; LDS counting sort (int atomics), then each wave owns
// 2 nodes. Wave splits into two 32-lane halves (rr) each taking a different
// record; half2 ez gathers cover both batches in one load.
__global__ __launch_bounds__(256) void accum_kernel(
    const __half2* __restrict__ ezh2, const unsigned int* __restrict__ payload,
    const int* __restrict__ cursor, const float4* __restrict__ a_tab4,
    const float* __restrict__ Watt, const float* __restrict__ batt,
    float* __restrict__ out) {
  __shared__ unsigned int rec[BIN_SLOTS];     // 4 KB
  __shared__ unsigned int sorted[BIN_SLOTS];  // 4 KB
  __shared__ int c8[NCLS];
  __shared__ int hist[NODES_PER_BIN];
  __shared__ int off[NODES_PER_BIN];
  __shared__ int cnt2[NODES_PER_BIN];
  int t = threadIdx.x;
  int bin = blockIdx.x >> 2;
  int quad = blockIdx.x & 3;
  if (t < NCLS) {
    int c = cursor[bin * NCLS + t];
    c8[t] = c > CLS_CAP ? CLS_CAP : c;
  }
  if (t < NODES_PER_BIN) { hist[t] = 0; cnt2[t] = 0; }
  __syncthreads();
  const unsigned int* seg = payload + (size_t)bin * BIN_SLOTS;
  for (int j = t; j < BIN_SLOTS; j += 256) {
    unsigned int r = seg[j];
    rec[j] = r;
    if ((j & (CLS_CAP - 1)) < c8[j >> 7]) atomicAdd(&hist[(r >> 11) & 31], 1);
  }
  __syncthreads();
  if (t < 64) {  // exclusive shuffle scan of 32 counts (wave 0)
    int v = (t < 32) ? hist[t] : 0;
    int orig = v;
#pragma unroll
    for (int d1 = 1; d1 < 32; d1 <<= 1) {
      int x = __shfl_up(v, d1, 64);
      if (t >= d1) v += x;
    }
    if (t < 32) off[t] = v - orig;
  }
  __syncthreads();
  for (int j = t; j < BIN_SLOTS; j += 256) {
    if ((j & (CLS_CAP - 1)) < c8[j >> 7]) {
      unsigned int r = rec[j];
      int nl = (r >> 11) & 31;
      sorted[off[nl] + atomicAdd(&cnt2[nl], 1)] = r;
    }
  }
  __syncthreads();

  int w = t >> 6, lane = t & 63, o = lane & 31, rr = lane >> 5;
  float wA = Watt[2 * OUT_DIM];
  float bA = batt[0];
  const float kInvQ = 1.0f / 2047.0f;
#pragma unroll
  for (int k = 0; k < 2; ++k) {
    int nl = quad * 8 + w * 2 + k;              // wave-uniform
    int n = bin * NODES_PER_BIN + nl;
    if (n >= N_NODES) break;
    int cn = hist[nl];
    int base = off[nl];
    float4 an = a_tab4[n];
    float adx = an.y, ady = an.w;               // a_d(n,b0), a_d(n,b1)
    float2 num = make_float2(0.f, 0.f), den = make_float2(0.f, 0.f);
    int i = 0;
    for (; i + 3 < cn; i += 4) {                // 2 records per half-wave iter
      unsigned int rA = sorted[base + i + rr];
      unsigned int rB = sorted[base + i + 2 + rr];
      int sA = rA >> 16, sB = rB >> 16;
      __half2 eA2 = ezh2[(size_t)sA * OUT_DIM + o];
      __half2 eB2 = ezh2[(size_t)sB * OUT_DIM + o];
      float4 aA = a_tab4[sA];
      float4 aB = a_tab4[sB];
      float wtA = fmaf((rA & 2047u) * kInvQ, wA, bA);
      float wtB = fmaf((rB & 2047u) * kInvQ, wA, bA);
      float l0A = aA.x + adx + wtA, l1A = aA.z + ady + wtA;
      float l0B = aB.x + adx + wtB, l1B = aB.z + ady + wtB;
      l0A = l0A > 0.f ? l0A : 0.01f * l0A;
      l1A = l1A > 0.f ? l1A : 0.01f * l1A;
      l0B = l0B > 0.f ? l0B : 0.01f * l0B;
      l1B = l1B > 0.f ? l1B : 0.01f * l1B;
      float2 eA = __half22float2(eA2);
      float2 eB = __half22float2(eB2);
      num.x = fmaf(eA.x, l0A, num.x); num.y = fmaf(eA.y, l1A, num.y);
      den.x += eA.x;                  den.y += eA.y;
      num.x = fmaf(eB.x, l0B, num.x); num.y = fmaf(eB.y, l1B, num.y);
      den.x += eB.x;                  den.y += eB.y;
    }
    for (; i < cn; i += 2) {                    // guarded tail
      int idx = i + rr;
      float m = (idx < cn) ? 1.f : 0.f;
      int idxc = (idx < cn) ? idx : cn - 1;
      unsigned int r = sorted[base + idxc];
      int s = r >> 16;
      __half2 e2 = ezh2[(size_t)s * OUT_DIM + o];
      float4 as4 = a_tab4[s];
      float wt = fmaf((r & 2047u) * kInvQ, wA, bA);
      float l0 = as4.x + adx + wt, l1 = as4.z + ady + wt;
      l0 = l0 > 0.f ? l0 : 0.01f * l0;
      l1 = l1 > 0.f ? l1 : 0.01f * l1;
      float2 e = __half22float2(e2);
      e.x *= m; e.y *= m;
      num.x = fmaf(e.x, l0, num.x); num.y = fmaf(e.y, l1, num.y);
      den.x += e.x;                 den.y += e.y;
    }
    // combine the two half-wave partials
    num.x += __shfl_xor(num.x, 32, 64);
    num.y += __shfl_xor(num.y, 32, 64);
    den.x += __shfl_xor(den.x, 32, 64);
    den.y += __shfl_xor(den.y, 32, 64);
    if (rr == 0) {
      float v0 = (cn > 0) ? num.x / den.x : 0.f;
      float v1 = (cn > 0) ? num.y / den.y : 0.f;
      out[((size_t)0 * N_NODES + n) * OUT_DIM + o] = v0;
      out[((size_t)1 * N_NODES + n) * OUT_DIM + o] = v1;
    }
  }
}

extern "C" void kernel_launch(void* const* d_in, const int* in_sizes, int n_in,
                              void* d_out, int out_size, void* d_ws, size_t ws_size,
                              hipStream_t stream) {
  const float* h      = (const float*)d_in[0];
  const float* weight = (const float*)d_in[1];
  const int*   src    = (const int*)d_in[2];
  const int*   dst    = (const int*)d_in[3];
  const float* Wfc    = (const float*)d_in[4];
  const float* bfc    = (const float*)d_in[5];
  const float* Watt   = (const float*)d_in[6];
  const float* batt   = (const float*)d_in[7];
  float* out = (float*)d_out;

  // workspace (~13.7 MB), same layout as R7
  float4*       a_tab   = (float4*)d_ws;                                  // 800 KB
  unsigned int* payload = (unsigned int*)(a_tab + N_NODES);               // 6.4 MB
  __half2*      ezh2    = (__half2*)(payload + (size_t)NBINS * BIN_SLOTS);// 6.4 MB
  int*          cursor  = (int*)(ezh2 + (size_t)N_NODES * OUT_DIM);       // ~50 KB

  hipMemsetAsync(cursor, 0, NCURS * sizeof(int), stream);
  fused_fc_scatter_kernel<<<SCATTER_BLOCKS + FC_BLOCKS, 256, 0, stream>>>(
      h, Wfc, bfc, Watt, src, dst, weight, ezh2, a_tab, cursor, payload);
  accum_kernel<<<NBINS * 4, 256, 0, stream>>>(ezh2, payload, cursor, a_tab,
                                              Watt, batt, out);
}